// Round 16
// baseline (104.930 us; speedup 1.0000x reference)
//
#include <hip/hip_runtime.h>

#define NHEADS 8
#define NB 512
#define NN 1000
#define DD 128
#define HH 128
#define SDIM 384              // D*CAT
#define NSPLIT 4              // blocks per batch: 2048 blocks = exactly 8/CU
#define NSLOT (NSPLIT * 4)    // one partial slot per wave (16)

// DPP helper: x += lane-permuted x. Pure VALU, no DS pipe.
template <int CTRL>
__device__ __forceinline__ float dpp_add(float x) {
    int y = __builtin_amdgcn_update_dpp(0, __float_as_int(x), CTRL, 0xf, 0xf, true);
    return x + __int_as_float(y);
}
#define DPP_QUAD_XOR1 0xB1   // quad_perm(1,0,3,2)
#define DPP_QUAD_XOR2 0x4E   // quad_perm(2,3,0,1)
#define DPP_HALF_MIRR 0x141  // mirror within 8
#define DPP_ROW_MIRR  0x140  // mirror within 16

// ---------------- kernel 0: per-batch qw precompute (coalesced) -------------
__global__ __launch_bounds__(256) void qw_kernel(
    const float* __restrict__ state_t,   // [B][384]
    const float* __restrict__ Wq,        // [128][384]
    const float* __restrict__ Wk,        // [128][128]
    float* __restrict__ qw)              // [B][8][128]
{
    const int b = blockIdx.x;
    const int t = threadIdx.x;
    const int lane = t & 63;
    const int w = t >> 6;

    __shared__ float s_q[HH];

    float st[6];
    #pragma unroll
    for (int j = 0; j < 6; ++j) st[j] = state_t[(size_t)b * SDIM + j * 64 + lane];

    for (int it = 0; it < 16; ++it) {
        const int r0 = w * 32 + it * 2;
        const float* w0 = Wq + (size_t)r0 * SDIM;
        const float* w1 = w0 + SDIM;
        float p0 = 0.f, p1 = 0.f;
        #pragma unroll
        for (int j = 0; j < 6; ++j) {
            p0 = fmaf(w0[j * 64 + lane], st[j], p0);
            p1 = fmaf(w1[j * 64 + lane], st[j], p1);
        }
        #pragma unroll
        for (int off = 32; off >= 1; off >>= 1) {
            p0 += __shfl_xor(p0, off, 64);
            p1 += __shfl_xor(p1, off, 64);
        }
        if (lane == 0) { s_q[r0] = p0; s_q[r0 + 1] = p1; }
    }
    __syncthreads();

    {
        const int d  = t & 127;
        const int h0 = (t >> 7) * 4;
        const float sc = 0.0625f * 1.4426950408889634f;  // (1/hd) * log2(e)
        for (int hh = 0; hh < 4; ++hh) {
            const int h = h0 + hh;
            float a = 0.f;
            #pragma unroll
            for (int j = 0; j < 16; ++j)
                a = fmaf(s_q[h * 16 + j], Wk[(size_t)(h * 16 + j) * DD + d], a);
            qw[(size_t)b * NHEADS * DD + h * DD + d] = a * sc;
        }
    }
}

// Async DMA: one wave64 instruction stages 1 KB (2 ctx rows) global -> LDS.
// LDS dest is wave-uniform base + lane*16 (HW rule); global src is per-lane.
__device__ __forceinline__ void dma16(const float* g, float* l) {
    __builtin_amdgcn_global_load_lds(
        (const __attribute__((address_space(1))) void*)g,
        (__attribute__((address_space(3))) void*)l,
        16, 0, 0);
}

#define WAITV(n) asm volatile("s_waitcnt vmcnt(" #n ")" ::: "memory")

// Wave-uniform mask for row k (runtime index ok: v_readlane with SGPR idx).
#define MSK(kidx) (__builtin_amdgcn_readlane(mv, (kidx)))

// Process one row held in LDS at float pointer LP (row base). Lane j of each
// 16-lane group consumes float4s j and j+16 of the row (2-way bank alias =
// free; 4 dup groups broadcast). ~52 VALU, skipped entirely for masked rows.
#define BODYL(LP)                                                             \
    {                                                                         \
        const float4 C0 = *reinterpret_cast<const float4*>((LP) + j * 4);     \
        const float4 C1 = *reinterpret_cast<const float4*>((LP) + 64 + j * 4);\
        float sa = C0.x * qa0.x, sb = C0.x * qb0.x;                           \
        sa = fmaf(C0.y, qa0.y, sa); sb = fmaf(C0.y, qb0.y, sb);               \
        sa = fmaf(C0.z, qa0.z, sa); sb = fmaf(C0.z, qb0.z, sb);               \
        sa = fmaf(C0.w, qa0.w, sa); sb = fmaf(C0.w, qb0.w, sb);               \
        sa = fmaf(C1.x, qa1.x, sa); sb = fmaf(C1.x, qb1.x, sb);               \
        sa = fmaf(C1.y, qa1.y, sa); sb = fmaf(C1.y, qb1.y, sb);               \
        sa = fmaf(C1.z, qa1.z, sa); sb = fmaf(C1.z, qb1.z, sb);               \
        sa = fmaf(C1.w, qa1.w, sa); sb = fmaf(C1.w, qb1.w, sb);               \
        sa = dpp_add<DPP_QUAD_XOR1>(sa); sb = dpp_add<DPP_QUAD_XOR1>(sb);     \
        sa = dpp_add<DPP_QUAD_XOR2>(sa); sb = dpp_add<DPP_QUAD_XOR2>(sb);     \
        sa = dpp_add<DPP_HALF_MIRR>(sa); sb = dpp_add<DPP_HALF_MIRR>(sb);     \
        sa = dpp_add<DPP_ROW_MIRR>(sa);  sb = dpp_add<DPP_ROW_MIRR>(sb);      \
        const float pa = exp2f(sa);                                           \
        const float pb = exp2f(sb);                                           \
        den0 += pa; den1 += pb;                                               \
        A0.x = fmaf(pa, C0.x, A0.x); B0.x = fmaf(pb, C0.x, B0.x);             \
        A0.y = fmaf(pa, C0.y, A0.y); B0.y = fmaf(pb, C0.y, B0.y);             \
        A0.z = fmaf(pa, C0.z, A0.z); B0.z = fmaf(pb, C0.z, B0.z);             \
        A0.w = fmaf(pa, C0.w, A0.w); B0.w = fmaf(pb, C0.w, B0.w);             \
        A1.x = fmaf(pa, C1.x, A1.x); B1.x = fmaf(pb, C1.x, B1.x);             \
        A1.y = fmaf(pa, C1.y, A1.y); B1.y = fmaf(pb, C1.y, B1.y);             \
        A1.z = fmaf(pa, C1.z, A1.z); B1.z = fmaf(pb, C1.z, B1.z);             \
        A1.w = fmaf(pa, C1.w, A1.w); B1.w = fmaf(pb, C1.w, B1.w);             \
    }

// One chunk = 2 rows from ring slot (c&3); masked rows skip reads + body.
#define CHUNK(c)                                                              \
    {                                                                         \
        const float* lrow = &sbuf[w][(c) & 3][0];                             \
        if (MSK(2 * (c)) == 0)     BODYL(lrow)                                \
        if (MSK(2 * (c) + 1) == 0) BODYL(lrow + 128)                          \
    }

// ---------------- kernel 1: partial score+softmax-accumulate ----------------
// Block = (split s, batch b), 256 threads = 4 waves; waves take 64/62/62/62
// contiguous rows (every DMA chunk fully in-bounds). Wave = 4 groups of 16
// lanes; group g = head pair (2g,2g+1); lane j owns float4s j and j+16 of
// each row. Context arrives via global_load_lds (1 DMA = 2 rows = 1KB),
// depth-4 per-wave LDS ring, counted vmcnt(3) steady state (never 0),
// peeled drain tail vmcnt(3/2/1/0). No barriers (per-wave-private ring).
// NO fence, NO atomics (R8: device fences ~0.7ms chip-wide).
__global__ __launch_bounds__(256, 4) void attn_partial_kernel(
    const float* __restrict__ context,   // [B][N][128]
    const int*   __restrict__ mask,      // [B][N]
    const float* __restrict__ qw,        // [B][8][128] (pre-scaled)
    float* __restrict__ part_acc,        // [B][NSLOT][8][128]
    float* __restrict__ part_den)        // [B][NSLOT][8]
{
    const int s = blockIdx.x;
    const int b = blockIdx.y;
    const int w = threadIdx.x >> 6;
    const int lane = threadIdx.x & 63;
    const int g = lane >> 4;     // head pair
    const int j = lane & 15;     // float4-slot within row (plus j+16)

    __shared__ float sbuf[4][4][256];    // [wave][ring slot][2 rows] = 16 KB

    const int cnt    = (w == 0) ? 64 : 62;
    const int chunks = cnt >> 1;         // 32 or 31
    const int row0   = s * 250 + ((w == 0) ? 0 : 64 + (w - 1) * 62);
    const float* gb  = context + ((size_t)b * NN + row0) * DD + lane * 4;
    const int*   mp  = mask + (size_t)b * NN + row0;

    // all row-masks in one lane-distributed load (clamped)
    const int mv = mp[lane < cnt ? lane : cnt - 1];

    // qw fragments for heads 2g, 2g+1 at d = j*4 and d = j*4+64 (16 regs)
    const float* qwb = qw + (size_t)b * NHEADS * DD + j * 4;
    const float4 qa0 = *reinterpret_cast<const float4*>(qwb + (2 * g) * DD);
    const float4 qa1 = *reinterpret_cast<const float4*>(qwb + (2 * g) * DD + 64);
    const float4 qb0 = *reinterpret_cast<const float4*>(qwb + (2 * g + 1) * DD);
    const float4 qb1 = *reinterpret_cast<const float4*>(qwb + (2 * g + 1) * DD + 64);

    float4 A0 = make_float4(0.f, 0.f, 0.f, 0.f), A1 = A0;  // acc head 2g
    float4 B0 = A0, B1 = A0;                                // acc head 2g+1
    float den0 = 0.f, den1 = 0.f;

    // prologue: stage chunks 0..3
    dma16(gb,            &sbuf[w][0][0]);
    dma16(gb + 1 * 256,  &sbuf[w][1][0]);
    dma16(gb + 2 * 256,  &sbuf[w][2][0]);
    dma16(gb + 3 * 256,  &sbuf[w][3][0]);

    // steady state: consume chunk c (vmcnt(3) -> oldest DMA landed), refill c+4
    #pragma unroll 1
    for (int c = 0; c < chunks - 4; ++c) {
        WAITV(3);
        CHUNK(c)
        __builtin_amdgcn_sched_barrier(0);   // pin refill after consumption
        dma16(gb + (size_t)(c + 4) * 256, &sbuf[w][(c + 4) & 3][0]);
    }
    // drain tail: no more issues; counted waits 3/2/1/0
    { const int c = chunks - 4; WAITV(3); CHUNK(c) }
    { const int c = chunks - 3; WAITV(2); CHUNK(c) }
    { const int c = chunks - 2; WAITV(1); CHUNK(c) }
    { const int c = chunks - 1; WAITV(0); CHUNK(c) }

    // ---- write this wave's partial slot (no barriers) ----
    const int slot = s * 4 + w;
    float* pa_ = part_acc + (((size_t)b * NSLOT + slot) * NHEADS) * DD + j * 4;
    *reinterpret_cast<float4*>(pa_ + (2 * g) * DD)          = A0;
    *reinterpret_cast<float4*>(pa_ + (2 * g) * DD + 64)     = A1;
    *reinterpret_cast<float4*>(pa_ + (2 * g + 1) * DD)      = B0;
    *reinterpret_cast<float4*>(pa_ + (2 * g + 1) * DD + 64) = B1;
    if (j == 0) {
        float* pd = part_den + ((size_t)b * NSLOT + slot) * NHEADS;
        pd[2 * g]     = den0;
        pd[2 * g + 1] = den1;
    }
}

// ---------------- kernel 2: combine slots + Wv/Wfc projections --------------
__global__ __launch_bounds__(128) void attn_combine_kernel(
    const float* __restrict__ part_acc,  // [B][NSLOT][8][128]
    const float* __restrict__ part_den,  // [B][NSLOT][8]
    const float* __restrict__ Wv,        // [128][128]
    const float* __restrict__ Wfc,       // [128][128]
    float* __restrict__ out)             // [B][128]
{
    const int b = blockIdx.x;
    const int t = threadIdx.x;   // 128 threads

    __shared__ float s_dn[NHEADS];
    __shared__ float s_ca[NHEADS][132];
    __shared__ float s_o2[HH];

    if (t < NHEADS) {
        float dn = 0.f;
        #pragma unroll
        for (int sp = 0; sp < NSLOT; ++sp)
            dn += part_den[((size_t)b * NSLOT + sp) * NHEADS + t];
        s_dn[t] = dn;
    }
    __syncthreads();

    {
        const int d = t;
        #pragma unroll
        for (int h = 0; h < NHEADS; ++h) {
            float a = 0.f;
            #pragma unroll
            for (int sp = 0; sp < NSLOT; ++sp)
                a += part_acc[(((size_t)b * NSLOT + sp) * NHEADS + h) * DD + d];
            s_ca[h][d] = a / s_dn[h];
        }
    }
    __syncthreads();

    {
        const int h = t >> 4;
        const float* wvr = Wv + (size_t)t * DD;
        float a = 0.f;
        #pragma unroll 4
        for (int d = 0; d < DD; ++d) a = fmaf(s_ca[h][d], wvr[d], a);
        s_o2[t] = a;
    }
    __syncthreads();

    {
        const float* wfc = Wfc + (size_t)t * DD;
        float a = 0.f;
        #pragma unroll 4
        for (int k = 0; k < DD; ++k) a = fmaf(s_o2[k], wfc[k], a);
        out[(size_t)b * HH + t] = a;
    }
}

extern "C" void kernel_launch(void* const* d_in, const int* in_sizes, int n_in,
                              void* d_out, int out_size, void* d_ws, size_t ws_size,
                              hipStream_t stream) {
    const float* state_t = (const float*)d_in[0];
    const float* context = (const float*)d_in[1];
    const int*   mask    = (const int*)d_in[2];
    const float* Wq      = (const float*)d_in[3];
    const float* Wk      = (const float*)d_in[4];
    const float* Wv      = (const float*)d_in[5];
    const float* Wfc     = (const float*)d_in[6];
    float* out = (float*)d_out;

    float* qw       = (float*)d_ws;                                  // 2 MB
    float* part_acc = qw + (size_t)NB * NHEADS * DD;                 // 33.5 MB
    float* part_den = part_acc + (size_t)NB * NSLOT * NHEADS * DD;   // 0.26 MB

    qw_kernel<<<dim3(NB), dim3(256), 0, stream>>>(state_t, Wq, Wk, qw);
    attn_partial_kernel<<<dim3(NSPLIT, NB), dim3(256), 0, stream>>>(
        context, mask, qw, part_acc, part_den);
    attn_combine_kernel<<<dim3(NB), dim3(128), 0, stream>>>(
        part_acc, part_den, Wv, Wfc, out);
}

// Round 17
// 95.948 us; speedup vs baseline: 1.0936x; 1.0936x over previous
//
#include <hip/hip_runtime.h>

#define NHEADS 8
#define NB 512
#define NN 1000
#define DD 128
#define HH 128
#define SDIM 384              // D*CAT
#define NSPLIT 4              // blocks per batch: 2048 blocks = EXACTLY 8/CU
#define NSLOT (NSPLIT * 4)    // one partial slot per wave (16)

// DPP helper: x += lane-permuted x. Pure VALU, no DS pipe.
template <int CTRL>
__device__ __forceinline__ float dpp_add(float x) {
    int y = __builtin_amdgcn_update_dpp(0, __float_as_int(x), CTRL, 0xf, 0xf, true);
    return x + __int_as_float(y);
}
#define DPP_QUAD_XOR1 0xB1   // quad_perm(1,0,3,2)
#define DPP_QUAD_XOR2 0x4E   // quad_perm(2,3,0,1)
#define DPP_HALF_MIRR 0x141  // mirror within 8
#define DPP_ROW_MIRR  0x140  // mirror within 16

// ---------------- kernel 0: per-batch qw precompute (coalesced) -------------
__global__ __launch_bounds__(256) void qw_kernel(
    const float* __restrict__ state_t,   // [B][384]
    const float* __restrict__ Wq,        // [128][384]
    const float* __restrict__ Wk,        // [128][128]
    float* __restrict__ qw)              // [B][8][128]
{
    const int b = blockIdx.x;
    const int t = threadIdx.x;
    const int lane = t & 63;
    const int w = t >> 6;

    __shared__ float s_q[HH];

    float st[6];
    #pragma unroll
    for (int j = 0; j < 6; ++j) st[j] = state_t[(size_t)b * SDIM + j * 64 + lane];

    for (int it = 0; it < 16; ++it) {
        const int r0 = w * 32 + it * 2;
        const float* w0 = Wq + (size_t)r0 * SDIM;
        const float* w1 = w0 + SDIM;
        float p0 = 0.f, p1 = 0.f;
        #pragma unroll
        for (int j = 0; j < 6; ++j) {
            p0 = fmaf(w0[j * 64 + lane], st[j], p0);
            p1 = fmaf(w1[j * 64 + lane], st[j], p1);
        }
        #pragma unroll
        for (int off = 32; off >= 1; off >>= 1) {
            p0 += __shfl_xor(p0, off, 64);
            p1 += __shfl_xor(p1, off, 64);
        }
        if (lane == 0) { s_q[r0] = p0; s_q[r0 + 1] = p1; }
    }
    __syncthreads();

    {
        const int d  = t & 127;
        const int h0 = (t >> 7) * 4;
        const float sc = 0.0625f * 1.4426950408889634f;  // (1/hd) * log2(e)
        for (int hh = 0; hh < 4; ++hh) {
            const int h = h0 + hh;
            float a = 0.f;
            #pragma unroll
            for (int j = 0; j < 16; ++j)
                a = fmaf(s_q[h * 16 + j], Wk[(size_t)(h * 16 + j) * DD + d], a);
            qw[(size_t)b * NHEADS * DD + h * DD + d] = a * sc;
        }
    }
}

// Wave-uniform mask for row k: SALU readlane from the lane-distributed mv.
#define MSK(kidx) (__builtin_amdgcn_readlane(mv, (kidx)))

// Conditionally load ctx row `idx` (clamped to cnt-1 via wave-uniform scalar
// select — rows past cnt-1 are dead prefetches; clamp keeps them in-bounds).
#define CLD(P, idx)                                                           \
    {                                                                         \
        const int _ci = (idx) < cnt ? (idx) : cnt - 1;                        \
        if (MSK(_ci) == 0) {                                                  \
            const float* _np = cp + (size_t)_ci * DD;                         \
            P##a = *reinterpret_cast<const float4*>(_np);                     \
            P##b = *reinterpret_cast<const float4*>(_np + 4);                 \
        }                                                                     \
    }

// Process row `idx` held in buffer P; whole body skipped for masked rows.
#define BODY(P, idx)                                                          \
    {                                                                         \
        if (MSK(idx) == 0) {                                                  \
            const float4 C0 = P##a, C1 = P##b;                                \
            float sa = C0.x * qa0.x, sb = C0.x * qb0.x;                       \
            sa = fmaf(C0.y, qa0.y, sa); sb = fmaf(C0.y, qb0.y, sb);           \
            sa = fmaf(C0.z, qa0.z, sa); sb = fmaf(C0.z, qb0.z, sb);           \
            sa = fmaf(C0.w, qa0.w, sa); sb = fmaf(C0.w, qb0.w, sb);           \
            sa = fmaf(C1.x, qa1.x, sa); sb = fmaf(C1.x, qb1.x, sb);           \
            sa = fmaf(C1.y, qa1.y, sa); sb = fmaf(C1.y, qb1.y, sb);           \
            sa = fmaf(C1.z, qa1.z, sa); sb = fmaf(C1.z, qb1.z, sb);           \
            sa = fmaf(C1.w, qa1.w, sa); sb = fmaf(C1.w, qb1.w, sb);           \
            sa = dpp_add<DPP_QUAD_XOR1>(sa); sb = dpp_add<DPP_QUAD_XOR1>(sb); \
            sa = dpp_add<DPP_QUAD_XOR2>(sa); sb = dpp_add<DPP_QUAD_XOR2>(sb); \
            sa = dpp_add<DPP_HALF_MIRR>(sa); sb = dpp_add<DPP_HALF_MIRR>(sb); \
            sa = dpp_add<DPP_ROW_MIRR>(sa);  sb = dpp_add<DPP_ROW_MIRR>(sb);  \
            const float pa = exp2f(sa);                                       \
            const float pb = exp2f(sb);                                       \
            den0 += pa; den1 += pb;                                           \
            A0.x = fmaf(pa, C0.x, A0.x); B0.x = fmaf(pb, C0.x, B0.x);         \
            A0.y = fmaf(pa, C0.y, A0.y); B0.y = fmaf(pb, C0.y, B0.y);         \
            A0.z = fmaf(pa, C0.z, A0.z); B0.z = fmaf(pb, C0.z, B0.z);         \
            A0.w = fmaf(pa, C0.w, A0.w); B0.w = fmaf(pb, C0.w, B0.w);         \
            A1.x = fmaf(pa, C1.x, A1.x); B1.x = fmaf(pb, C1.x, B1.x);         \
            A1.y = fmaf(pa, C1.y, A1.y); B1.y = fmaf(pb, C1.y, B1.y);         \
            A1.z = fmaf(pa, C1.z, A1.z); B1.z = fmaf(pb, C1.z, B1.z);         \
            A1.w = fmaf(pa, C1.w, A1.w); B1.w = fmaf(pb, C1.w, B1.w);         \
        }                                                                     \
    }

// ---------------- kernel 1: partial score+softmax-accumulate ----------------
// Block = (split s, batch b), 256 threads = 4 waves; block owns 250 rows,
// waves take 63/63/62/62 contiguous rows. Wave = 4 groups of 16 lanes; group
// g = head pair (2g,2g+1); lane j owns floats [j*8, j*8+8). All row-masks in
// one lane-distributed vector (readlane). Masked rows skip body AND loads.
// Grid = 2048 blocks = EXACTLY 8 blocks/CU (32 waves/CU, single round, zero
// residency tail). NO fence, NO atomics (R8: device fences ~0.7ms chip-wide).
__global__ __launch_bounds__(256, 4) void attn_partial_kernel(
    const float* __restrict__ context,   // [B][N][128]
    const int*   __restrict__ mask,      // [B][N]
    const float* __restrict__ qw,        // [B][8][128] (pre-scaled)
    float* __restrict__ part_acc,        // [B][NSLOT][8][128]
    float* __restrict__ part_den)        // [B][NSLOT][8]
{
    const int s = blockIdx.x;
    const int b = blockIdx.y;
    const int w = threadIdx.x >> 6;
    const int lane = threadIdx.x & 63;
    const int g = lane >> 4;     // head pair
    const int j = lane & 15;     // d-slice

    const int cnt  = (w < 2) ? 63 : 62;
    const int row0 = s * 250 + ((w < 2) ? w * 63 : 126 + (w - 2) * 62);
    const float* cp = context + ((size_t)b * NN + row0) * DD + j * 8;
    const int*   mp = mask + (size_t)b * NN + row0;

    // one load: lane i holds mask of row i (clamped; cnt <= 63 < 64)
    const int mv = mp[lane < cnt ? lane : cnt - 1];

    // qw slices for heads 2g, 2g+1 (16 regs)
    const float* qwb = qw + (size_t)b * NHEADS * DD + j * 8;
    const float4 qa0 = *reinterpret_cast<const float4*>(qwb + (2 * g) * DD);
    const float4 qa1 = *reinterpret_cast<const float4*>(qwb + (2 * g) * DD + 4);
    const float4 qb0 = *reinterpret_cast<const float4*>(qwb + (2 * g + 1) * DD);
    const float4 qb1 = *reinterpret_cast<const float4*>(qwb + (2 * g + 1) * DD + 4);

    float4 A0 = make_float4(0.f, 0.f, 0.f, 0.f), A1 = A0;  // acc head 2g
    float4 B0 = A0, B1 = A0;                                // acc head 2g+1
    float den0 = 0.f, den1 = 0.f;

    // 3 rotating single-row buffers (named locals)
    float4 p0a, p0b;
    float4 p1a, p1b;
    float4 p2a, p2b;
    CLD(p0, 0)
    CLD(p1, 1)
    CLD(p2, 2)

    // rows 0..59: 20 triple rounds; ctx prefetch +3 (clamped to cnt-1)
    for (int it = 0; it < 20; ++it) {
        const int k = 3 * it;
        BODY(p0, k)     CLD(p0, k + 3)
        BODY(p1, k + 1) CLD(p1, k + 4)
        BODY(p2, k + 2) CLD(p2, k + 5)
    }
    // peeled tail: rows 60, 61, and (waves 0-1 only) 62
    BODY(p0, 60)
    BODY(p1, 61)
    if (cnt > 62) BODY(p2, 62)

    // ---- write this wave's partial slot (no LDS, no barrier) ----
    const int slot = s * 4 + w;
    float* pa_ = part_acc + (((size_t)b * NSLOT + slot) * NHEADS) * DD + j * 8;
    *reinterpret_cast<float4*>(pa_ + (2 * g) * DD)         = A0;
    *reinterpret_cast<float4*>(pa_ + (2 * g) * DD + 4)     = A1;
    *reinterpret_cast<float4*>(pa_ + (2 * g + 1) * DD)     = B0;
    *reinterpret_cast<float4*>(pa_ + (2 * g + 1) * DD + 4) = B1;
    if (j == 0) {
        float* pd = part_den + ((size_t)b * NSLOT + slot) * NHEADS;
        pd[2 * g]     = den0;
        pd[2 * g + 1] = den1;
    }
}

// ---------------- kernel 2: combine slots + Wv/Wfc projections --------------
__global__ __launch_bounds__(128) void attn_combine_kernel(
    const float* __restrict__ part_acc,  // [B][NSLOT][8][128]
    const float* __restrict__ part_den,  // [B][NSLOT][8]
    const float* __restrict__ Wv,        // [128][128]
    const float* __restrict__ Wfc,       // [128][128]
    float* __restrict__ out)             // [B][128]
{
    const int b = blockIdx.x;
    const int t = threadIdx.x;   // 128 threads

    __shared__ float s_dn[NHEADS];
    __shared__ float s_ca[NHEADS][132];
    __shared__ float s_o2[HH];

    if (t < NHEADS) {
        float dn = 0.f;
        #pragma unroll
        for (int sp = 0; sp < NSLOT; ++sp)
            dn += part_den[((size_t)b * NSLOT + sp) * NHEADS + t];
        s_dn[t] = dn;
    }
    __syncthreads();

    {
        const int d = t;
        #pragma unroll
        for (int h = 0; h < NHEADS; ++h) {
            float a = 0.f;
            #pragma unroll
            for (int sp = 0; sp < NSLOT; ++sp)
                a += part_acc[(((size_t)b * NSLOT + sp) * NHEADS + h) * DD + d];
            s_ca[h][d] = a / s_dn[h];
        }
    }
    __syncthreads();

    {
        const int h = t >> 4;
        const float* wvr = Wv + (size_t)t * DD;
        float a = 0.f;
        #pragma unroll 4
        for (int d = 0; d < DD; ++d) a = fmaf(s_ca[h][d], wvr[d], a);
        s_o2[t] = a;
    }
    __syncthreads();

    {
        const float* wfc = Wfc + (size_t)t * DD;
        float a = 0.f;
        #pragma unroll 4
        for (int k = 0; k < DD; ++k) a = fmaf(s_o2[k], wfc[k], a);
        out[(size_t)b * HH + t] = a;
    }
}

extern "C" void kernel_launch(void* const* d_in, const int* in_sizes, int n_in,
                              void* d_out, int out_size, void* d_ws, size_t ws_size,
                              hipStream_t stream) {
    const float* state_t = (const float*)d_in[0];
    const float* context = (const float*)d_in[1];
    const int*   mask    = (const int*)d_in[2];
    const float* Wq      = (const float*)d_in[3];
    const float* Wk      = (const float*)d_in[4];
    const float* Wv      = (const float*)d_in[5];
    const float* Wfc     = (const float*)d_in[6];
    float* out = (float*)d_out;

    float* qw       = (float*)d_ws;                                  // 2 MB
    float* part_acc = qw + (size_t)NB * NHEADS * DD;                 // 33.5 MB
    float* part_den = part_acc + (size_t)NB * NSLOT * NHEADS * DD;   // 0.26 MB

    qw_kernel<<<dim3(NB), dim3(256), 0, stream>>>(state_t, Wq, Wk, qw);
    attn_partial_kernel<<<dim3(NSPLIT, NB), dim3(256), 0, stream>>>(
        context, mask, qw, part_acc, part_den);
    attn_combine_kernel<<<dim3(NB), dim3(128), 0, stream>>>(
        part_acc, part_den, Wv, Wfc, out);
}

// Round 18
// 91.603 us; speedup vs baseline: 1.1455x; 1.0474x over previous
//
#include <hip/hip_runtime.h>

#define NHEADS 8
#define NB 512
#define NN 1000
#define DD 128
#define HH 128
#define SDIM 384              // D*CAT
#define NSPLIT 4              // blocks per batch: 2048 blocks = exactly 8/CU
#define NSLOT (NSPLIT * 4)    // one partial slot per wave (16)

// DPP helper: x += lane-permuted x. Pure VALU, no DS pipe.
template <int CTRL>
__device__ __forceinline__ float dpp_add(float x) {
    int y = __builtin_amdgcn_update_dpp(0, __float_as_int(x), CTRL, 0xf, 0xf, true);
    return x + __int_as_float(y);
}
#define DPP_QUAD_XOR1 0xB1   // quad_perm(1,0,3,2)
#define DPP_QUAD_XOR2 0x4E   // quad_perm(2,3,0,1)
#define DPP_HALF_MIRR 0x141  // mirror within 8
#define DPP_ROW_MIRR  0x140  // mirror within 16

// ---------------- kernel 0: per-batch qw precompute (coalesced) -------------
__global__ __launch_bounds__(256) void qw_kernel(
    const float* __restrict__ state_t,   // [B][384]
    const float* __restrict__ Wq,        // [128][384]
    const float* __restrict__ Wk,        // [128][128]
    float* __restrict__ qw)              // [B][8][128]
{
    const int b = blockIdx.x;
    const int t = threadIdx.x;
    const int lane = t & 63;
    const int w = t >> 6;

    __shared__ float s_q[HH];

    float st[6];
    #pragma unroll
    for (int j = 0; j < 6; ++j) st[j] = state_t[(size_t)b * SDIM + j * 64 + lane];

    for (int it = 0; it < 16; ++it) {
        const int r0 = w * 32 + it * 2;
        const float* w0 = Wq + (size_t)r0 * SDIM;
        const float* w1 = w0 + SDIM;
        float p0 = 0.f, p1 = 0.f;
        #pragma unroll
        for (int j = 0; j < 6; ++j) {
            p0 = fmaf(w0[j * 64 + lane], st[j], p0);
            p1 = fmaf(w1[j * 64 + lane], st[j], p1);
        }
        #pragma unroll
        for (int off = 32; off >= 1; off >>= 1) {
            p0 += __shfl_xor(p0, off, 64);
            p1 += __shfl_xor(p1, off, 64);
        }
        if (lane == 0) { s_q[r0] = p0; s_q[r0 + 1] = p1; }
    }
    __syncthreads();

    {
        const int d  = t & 127;
        const int h0 = (t >> 7) * 4;
        const float sc = 0.0625f * 1.4426950408889634f;  // (1/hd) * log2(e)
        for (int hh = 0; hh < 4; ++hh) {
            const int h = h0 + hh;
            float a = 0.f;
            #pragma unroll
            for (int j = 0; j < 16; ++j)
                a = fmaf(s_q[h * 16 + j], Wk[(size_t)(h * 16 + j) * DD + d], a);
            qw[(size_t)b * NHEADS * DD + h * DD + d] = a * sc;
        }
    }
}

#define RDL(v, k) (__builtin_amdgcn_readlane((v), (k)))

// Load the row for iteration `k` (clamped to lane 62) into buffer P.
// Row index comes from the lane-distributed compacted list iv (SGPR via
// readlane) -> scalar-base addressing, NO branch.
#define CLD2(P, k)                                                            \
    {                                                                         \
        const int _kk = (k) < 62 ? (k) : 62;                                  \
        const int _row = RDL(iv, _kk);                                        \
        const float* _np = cp + (size_t)_row * DD;                            \
        P##a = *reinterpret_cast<const float4*>(_np);                         \
        P##b = *reinterpret_cast<const float4*>(_np + 4);                     \
    }

// Process iteration `k` from buffer P. Uniform weight kills pad slots
// (k >= niter); everything else is the proven R14 math. NO branch.
#define BODY2(P, k)                                                           \
    {                                                                         \
        const float wt = ((k) < niter) ? 1.f : 0.f;                           \
        const float4 C0 = P##a, C1 = P##b;                                    \
        float sa = C0.x * qa0.x, sb = C0.x * qb0.x;                           \
        sa = fmaf(C0.y, qa0.y, sa); sb = fmaf(C0.y, qb0.y, sb);               \
        sa = fmaf(C0.z, qa0.z, sa); sb = fmaf(C0.z, qb0.z, sb);               \
        sa = fmaf(C0.w, qa0.w, sa); sb = fmaf(C0.w, qb0.w, sb);               \
        sa = fmaf(C1.x, qa1.x, sa); sb = fmaf(C1.x, qb1.x, sb);               \
        sa = fmaf(C1.y, qa1.y, sa); sb = fmaf(C1.y, qb1.y, sb);               \
        sa = fmaf(C1.z, qa1.z, sa); sb = fmaf(C1.z, qb1.z, sb);               \
        sa = fmaf(C1.w, qa1.w, sa); sb = fmaf(C1.w, qb1.w, sb);               \
        sa = dpp_add<DPP_QUAD_XOR1>(sa); sb = dpp_add<DPP_QUAD_XOR1>(sb);     \
        sa = dpp_add<DPP_QUAD_XOR2>(sa); sb = dpp_add<DPP_QUAD_XOR2>(sb);     \
        sa = dpp_add<DPP_HALF_MIRR>(sa); sb = dpp_add<DPP_HALF_MIRR>(sb);     \
        sa = dpp_add<DPP_ROW_MIRR>(sa);  sb = dpp_add<DPP_ROW_MIRR>(sb);      \
        const float pa = exp2f(sa) * wt;                                      \
        const float pb = exp2f(sb) * wt;                                      \
        den0 += pa; den1 += pb;                                               \
        A0.x = fmaf(pa, C0.x, A0.x); B0.x = fmaf(pb, C0.x, B0.x);             \
        A0.y = fmaf(pa, C0.y, A0.y); B0.y = fmaf(pb, C0.y, B0.y);             \
        A0.z = fmaf(pa, C0.z, A0.z); B0.z = fmaf(pb, C0.z, B0.z);             \
        A0.w = fmaf(pa, C0.w, A0.w); B0.w = fmaf(pb, C0.w, B0.w);             \
        A1.x = fmaf(pa, C1.x, A1.x); B1.x = fmaf(pb, C1.x, B1.x);             \
        A1.y = fmaf(pa, C1.y, A1.y); B1.y = fmaf(pb, C1.y, B1.y);             \
        A1.z = fmaf(pa, C1.z, A1.z); B1.z = fmaf(pb, C1.z, B1.z);             \
        A1.w = fmaf(pa, C1.w, A1.w); B1.w = fmaf(pb, C1.w, B1.w);             \
    }

// ---------------- kernel 1: partial score+softmax-accumulate ----------------
// Block = (split s, batch b), 256 threads = 4 waves; block owns 250 rows.
// Phase A: compact unmasked row indices into LDS (ballot + popc prefix).
// Phase B: waves consume the active list round-robin (wave w -> slots
// w, w+4, ...): per-wave balance +-1 row, ZERO per-row branches, no masked
// work, unconditional scalar-base loads. Wave = 4 dup groups of 16 lanes;
// group g = head pair (2g,2g+1); lane j owns floats [j*8, j*8+8).
// NO fence, NO atomics (R8: device fences ~0.7ms chip-wide).
__global__ __launch_bounds__(256, 4) void attn_partial_kernel(
    const float* __restrict__ context,   // [B][N][128]
    const int*   __restrict__ mask,      // [B][N]
    const float* __restrict__ qw,        // [B][8][128] (pre-scaled)
    float* __restrict__ part_acc,        // [B][NSLOT][8][128]
    float* __restrict__ part_den)        // [B][NSLOT][8]
{
    const int s = blockIdx.x;
    const int b = blockIdx.y;
    const int w = threadIdx.x >> 6;
    const int lane = threadIdx.x & 63;
    const int g = lane >> 4;     // head pair
    const int j = lane & 15;     // d-slice

    __shared__ unsigned long long s_bal[4];
    __shared__ int s_idx[256];

    const int*   mp = mask + (size_t)b * NN + s * 250;
    const float* cp = context + ((size_t)b * NN + s * 250) * DD + j * 8;

    // ---- phase A: compact unmasked rows of this block's 250 ----
    {
        const int rowA = w * 64 + lane;                     // 0..255
        const int m = mp[rowA < 250 ? rowA : 249];
        const bool act = (rowA < 250) && (m == 0);
        const unsigned long long bal = __ballot(act);
        if (lane == 0) s_bal[w] = bal;
        __syncthreads();
        int base = 0;
        #pragma unroll
        for (int ww = 0; ww < 4; ++ww)
            if (ww < w) base += __popcll(s_bal[ww]);
        if (act) {
            const unsigned long long below = bal & ((1ull << lane) - 1ull);
            s_idx[base + __popcll(below)] = rowA;
        }
        __syncthreads();
    }
    const int nact = __popcll(s_bal[0]) + __popcll(s_bal[1])
                   + __popcll(s_bal[2]) + __popcll(s_bal[3]);

    // iterations this wave owns (slots w, w+4, ...)
    const int niter  = (nact > w) ? ((nact - w + 3) >> 2) : 0;
    const int niter3 = ((niter + 2) / 3) * 3;               // <= 63

    // lane i holds the row for iteration i (pad -> row 0, weight 0)
    const int slot = w + 4 * lane;
    const int iv = (slot < nact) ? s_idx[slot] : 0;

    // qw slices for heads 2g, 2g+1 (16 regs)
    const float* qwb = qw + (size_t)b * NHEADS * DD + j * 8;
    const float4 qa0 = *reinterpret_cast<const float4*>(qwb + (2 * g) * DD);
    const float4 qa1 = *reinterpret_cast<const float4*>(qwb + (2 * g) * DD + 4);
    const float4 qb0 = *reinterpret_cast<const float4*>(qwb + (2 * g + 1) * DD);
    const float4 qb1 = *reinterpret_cast<const float4*>(qwb + (2 * g + 1) * DD + 4);

    float4 A0 = make_float4(0.f, 0.f, 0.f, 0.f), A1 = A0;  // acc head 2g
    float4 B0 = A0, B1 = A0;                                // acc head 2g+1
    float den0 = 0.f, den1 = 0.f;

    // 3 rotating single-row buffers (named locals)
    float4 p0a, p0b;
    float4 p1a, p1b;
    float4 p2a, p2b;
    CLD2(p0, 0)
    CLD2(p1, 1)
    CLD2(p2, 2)

    #pragma unroll 1
    for (int k = 0; k < niter3; k += 3) {
        BODY2(p0, k)     CLD2(p0, k + 3)
        BODY2(p1, k + 1) CLD2(p1, k + 4)
        BODY2(p2, k + 2) CLD2(p2, k + 5)
    }

    // ---- write this wave's partial slot (no barrier needed after) ----
    const int oslot = s * 4 + w;
    float* pa_ = part_acc + (((size_t)b * NSLOT + oslot) * NHEADS) * DD + j * 8;
    *reinterpret_cast<float4*>(pa_ + (2 * g) * DD)         = A0;
    *reinterpret_cast<float4*>(pa_ + (2 * g) * DD + 4)     = A1;
    *reinterpret_cast<float4*>(pa_ + (2 * g + 1) * DD)     = B0;
    *reinterpret_cast<float4*>(pa_ + (2 * g + 1) * DD + 4) = B1;
    if (j == 0) {
        float* pd = part_den + ((size_t)b * NSLOT + oslot) * NHEADS;
        pd[2 * g]     = den0;
        pd[2 * g + 1] = den1;
    }
}

// ---------------- kernel 2: combine slots + Wv/Wfc projections --------------
__global__ __launch_bounds__(128) void attn_combine_kernel(
    const float* __restrict__ part_acc,  // [B][NSLOT][8][128]
    const float* __restrict__ part_den,  // [B][NSLOT][8]
    const float* __restrict__ Wv,        // [128][128]
    const float* __restrict__ Wfc,       // [128][128]
    float* __restrict__ out)             // [B][128]
{
    const int b = blockIdx.x;
    const int t = threadIdx.x;   // 128 threads

    __shared__ float s_dn[NHEADS];
    __shared__ float s_ca[NHEADS][132];
    __shared__ float s_o2[HH];

    if (t < NHEADS) {
        float dn = 0.f;
        #pragma unroll
        for (int sp = 0; sp < NSLOT; ++sp)
            dn += part_den[((size_t)b * NSLOT + sp) * NHEADS + t];
        s_dn[t] = dn;
    }
    __syncthreads();

    {
        const int d = t;
        #pragma unroll
        for (int h = 0; h < NHEADS; ++h) {
            float a = 0.f;
            #pragma unroll
            for (int sp = 0; sp < NSLOT; ++sp)
                a += part_acc[(((size_t)b * NSLOT + sp) * NHEADS + h) * DD + d];
            s_ca[h][d] = a / s_dn[h];
        }
    }
    __syncthreads();

    {
        const int h = t >> 4;
        const float* wvr = Wv + (size_t)t * DD;
        float a = 0.f;
        #pragma unroll 4
        for (int d = 0; d < DD; ++d) a = fmaf(s_ca[h][d], wvr[d], a);
        s_o2[t] = a;
    }
    __syncthreads();

    {
        const float* wfc = Wfc + (size_t)t * DD;
        float a = 0.f;
        #pragma unroll 4
        for (int k = 0; k < DD; ++k) a = fmaf(s_o2[k], wfc[k], a);
        out[(size_t)b * HH + t] = a;
    }
}

extern "C" void kernel_launch(void* const* d_in, const int* in_sizes, int n_in,
                              void* d_out, int out_size, void* d_ws, size_t ws_size,
                              hipStream_t stream) {
    const float* state_t = (const float*)d_in[0];
    const float* context = (const float*)d_in[1];
    const int*   mask    = (const int*)d_in[2];
    const float* Wq      = (const float*)d_in[3];
    const float* Wk      = (const float*)d_in[4];
    const float* Wv      = (const float*)d_in[5];
    const float* Wfc     = (const float*)d_in[6];
    float* out = (float*)d_out;

    float* qw       = (float*)d_ws;                                  // 2 MB
    float* part_acc = qw + (size_t)NB * NHEADS * DD;                 // 33.5 MB
    float* part_den = part_acc + (size_t)NB * NSLOT * NHEADS * DD;   // 0.26 MB

    qw_kernel<<<dim3(NB), dim3(256), 0, stream>>>(state_t, Wq, Wk, qw);
    attn_partial_kernel<<<dim3(NSPLIT, NB), dim3(256), 0, stream>>>(
        context, mask, qw, part_acc, part_den);
    attn_combine_kernel<<<dim3(NB), dim3(128), 0, stream>>>(
        part_acc, part_den, Wv, Wfc, out);
}

// Round 19
// 91.308 us; speedup vs baseline: 1.1492x; 1.0032x over previous
//
#include <hip/hip_runtime.h>

#define NHEADS 8
#define NB 512
#define NN 1000
#define DD 128
#define HH 128
#define SDIM 384              // D*CAT
#define NSPLIT 4              // blocks per batch: 2048 blocks = exactly 8/CU
#define NSLOT (NSPLIT * 4)    // one partial slot per wave (16)

// DPP helper: x += lane-permuted x. Pure VALU, no DS pipe.
template <int CTRL>
__device__ __forceinline__ float dpp_add(float x) {
    int y = __builtin_amdgcn_update_dpp(0, __float_as_int(x), CTRL, 0xf, 0xf, true);
    return x + __int_as_float(y);
}
#define DPP_QUAD_XOR1 0xB1   // quad_perm(1,0,3,2)
#define DPP_QUAD_XOR2 0x4E   // quad_perm(2,3,0,1)
#define DPP_HALF_MIRR 0x141  // mirror within 8
#define DPP_ROW_MIRR  0x140  // mirror within 16

// ---------------- kernel 0: per-batch qw precompute (coalesced) -------------
__global__ __launch_bounds__(256) void qw_kernel(
    const float* __restrict__ state_t,   // [B][384]
    const float* __restrict__ Wq,        // [128][384]
    const float* __restrict__ Wk,        // [128][128]
    float* __restrict__ qw)              // [B][8][128]
{
    const int b = blockIdx.x;
    const int t = threadIdx.x;
    const int lane = t & 63;
    const int w = t >> 6;

    __shared__ float s_q[HH];

    float st[6];
    #pragma unroll
    for (int j = 0; j < 6; ++j) st[j] = state_t[(size_t)b * SDIM + j * 64 + lane];

    for (int it = 0; it < 16; ++it) {
        const int r0 = w * 32 + it * 2;
        const float* w0 = Wq + (size_t)r0 * SDIM;
        const float* w1 = w0 + SDIM;
        float p0 = 0.f, p1 = 0.f;
        #pragma unroll
        for (int j = 0; j < 6; ++j) {
            p0 = fmaf(w0[j * 64 + lane], st[j], p0);
            p1 = fmaf(w1[j * 64 + lane], st[j], p1);
        }
        #pragma unroll
        for (int off = 32; off >= 1; off >>= 1) {
            p0 += __shfl_xor(p0, off, 64);
            p1 += __shfl_xor(p1, off, 64);
        }
        if (lane == 0) { s_q[r0] = p0; s_q[r0 + 1] = p1; }
    }
    __syncthreads();

    {
        const int d  = t & 127;
        const int h0 = (t >> 7) * 4;
        const float sc = 0.0625f * 1.4426950408889634f;  // (1/hd) * log2(e)
        for (int hh = 0; hh < 4; ++hh) {
            const int h = h0 + hh;
            float a = 0.f;
            #pragma unroll
            for (int j = 0; j < 16; ++j)
                a = fmaf(s_q[h * 16 + j], Wk[(size_t)(h * 16 + j) * DD + d], a);
            qw[(size_t)b * NHEADS * DD + h * DD + d] = a * sc;
        }
    }
}

#define RDL(v, k) (__builtin_amdgcn_readlane((v), (k)))

// Load the row for iteration `k` (clamped to lane 62) into buffer P.
// DENSE split: lane j reads 16B at row+j*16 (first half) and row+256B+j*16
// (second half) -> each dwordx4 is a contiguous 256B quarter-wave segment.
#define CLD2(P, k)                                                            \
    {                                                                         \
        const int _kk = (k) < 62 ? (k) : 62;                                  \
        const int _row = RDL(iv, _kk);                                        \
        const float* _np = cp + (size_t)_row * DD;                            \
        P##a = *reinterpret_cast<const float4*>(_np);                         \
        P##b = *reinterpret_cast<const float4*>(_np + 64);                    \
    }

// Process iteration `k` from buffer P. Uniform weight kills pad slots
// (k >= niter). NO branch.
#define BODY2(P, k)                                                           \
    {                                                                         \
        const float wt = ((k) < niter) ? 1.f : 0.f;                           \
        const float4 C0 = P##a, C1 = P##b;                                    \
        float sa = C0.x * qa0.x, sb = C0.x * qb0.x;                           \
        sa = fmaf(C0.y, qa0.y, sa); sb = fmaf(C0.y, qb0.y, sb);               \
        sa = fmaf(C0.z, qa0.z, sa); sb = fmaf(C0.z, qb0.z, sb);               \
        sa = fmaf(C0.w, qa0.w, sa); sb = fmaf(C0.w, qb0.w, sb);               \
        sa = fmaf(C1.x, qa1.x, sa); sb = fmaf(C1.x, qb1.x, sb);               \
        sa = fmaf(C1.y, qa1.y, sa); sb = fmaf(C1.y, qb1.y, sb);               \
        sa = fmaf(C1.z, qa1.z, sa); sb = fmaf(C1.z, qb1.z, sb);               \
        sa = fmaf(C1.w, qa1.w, sa); sb = fmaf(C1.w, qb1.w, sb);               \
        sa = dpp_add<DPP_QUAD_XOR1>(sa); sb = dpp_add<DPP_QUAD_XOR1>(sb);     \
        sa = dpp_add<DPP_QUAD_XOR2>(sa); sb = dpp_add<DPP_QUAD_XOR2>(sb);     \
        sa = dpp_add<DPP_HALF_MIRR>(sa); sb = dpp_add<DPP_HALF_MIRR>(sb);     \
        sa = dpp_add<DPP_ROW_MIRR>(sa);  sb = dpp_add<DPP_ROW_MIRR>(sb);      \
        const float pa = exp2f(sa) * wt;                                      \
        const float pb = exp2f(sb) * wt;                                      \
        den0 += pa; den1 += pb;                                               \
        A0.x = fmaf(pa, C0.x, A0.x); B0.x = fmaf(pb, C0.x, B0.x);             \
        A0.y = fmaf(pa, C0.y, A0.y); B0.y = fmaf(pb, C0.y, B0.y);             \
        A0.z = fmaf(pa, C0.z, A0.z); B0.z = fmaf(pb, C0.z, B0.z);             \
        A0.w = fmaf(pa, C0.w, A0.w); B0.w = fmaf(pb, C0.w, B0.w);             \
        A1.x = fmaf(pa, C1.x, A1.x); B1.x = fmaf(pb, C1.x, B1.x);             \
        A1.y = fmaf(pa, C1.y, A1.y); B1.y = fmaf(pb, C1.y, B1.y);             \
        A1.z = fmaf(pa, C1.z, A1.z); B1.z = fmaf(pb, C1.z, B1.z);             \
        A1.w = fmaf(pa, C1.w, A1.w); B1.w = fmaf(pb, C1.w, B1.w);             \
    }

// ---------------- kernel 1: partial score+softmax-accumulate ----------------
// Block = (split s, batch b), 256 threads = 4 waves; block owns 250 rows.
// Phase A: compact unmasked row indices into LDS (ballot + popc prefix).
// Phase B: waves consume the active list round-robin (wave w -> slots
// w, w+4, ...): per-wave balance +-1 row, zero per-row branches, no masked
// work, unconditional scalar-base loads. Wave = 4 dup groups of 16 lanes;
// group g = head pair (2g,2g+1); lane j owns floats [j*4,j*4+4) and
// [64+j*4, 64+j*4+4)  (DENSE 256B quarter-wave segments per load — the
// j*8 split was stride-32B sparse, 2x the TA line-touches).
// NO fence, NO atomics (R8: device fences ~0.7ms chip-wide).
__global__ __launch_bounds__(256, 4) void attn_partial_kernel(
    const float* __restrict__ context,   // [B][N][128]
    const int*   __restrict__ mask,      // [B][N]
    const float* __restrict__ qw,        // [B][8][128] (pre-scaled)
    float* __restrict__ part_acc,        // [B][NSLOT][8][128]
    float* __restrict__ part_den)        // [B][NSLOT][8]
{
    const int s = blockIdx.x;
    const int b = blockIdx.y;
    const int w = threadIdx.x >> 6;
    const int lane = threadIdx.x & 63;
    const int g = lane >> 4;     // head pair
    const int j = lane & 15;     // d-slice

    __shared__ unsigned long long s_bal[4];
    __shared__ int s_idx[256];

    const int*   mp = mask + (size_t)b * NN + s * 250;
    const float* cp = context + ((size_t)b * NN + s * 250) * DD + j * 4;

    // ---- phase A: compact unmasked rows of this block's 250 ----
    {
        const int rowA = w * 64 + lane;                     // 0..255
        const int m = mp[rowA < 250 ? rowA : 249];
        const bool act = (rowA < 250) && (m == 0);
        const unsigned long long bal = __ballot(act);
        if (lane == 0) s_bal[w] = bal;
        __syncthreads();
        int base = 0;
        #pragma unroll
        for (int ww = 0; ww < 4; ++ww)
            if (ww < w) base += __popcll(s_bal[ww]);
        if (act) {
            const unsigned long long below = bal & ((1ull << lane) - 1ull);
            s_idx[base + __popcll(below)] = rowA;
        }
        __syncthreads();
    }
    const int nact = __popcll(s_bal[0]) + __popcll(s_bal[1])
                   + __popcll(s_bal[2]) + __popcll(s_bal[3]);

    // iterations this wave owns (slots w, w+4, ...)
    const int niter  = (nact > w) ? ((nact - w + 3) >> 2) : 0;
    const int niter3 = ((niter + 2) / 3) * 3;               // <= 63

    // lane i holds the row for iteration i (pad -> row 0, weight 0)
    const int slot = w + 4 * lane;
    const int iv = (slot < nact) ? s_idx[slot] : 0;

    // qw fragments for heads 2g, 2g+1 at d = j*4 and d = 64+j*4 (16 regs)
    const float* qwb = qw + (size_t)b * NHEADS * DD + j * 4;
    const float4 qa0 = *reinterpret_cast<const float4*>(qwb + (2 * g) * DD);
    const float4 qa1 = *reinterpret_cast<const float4*>(qwb + (2 * g) * DD + 64);
    const float4 qb0 = *reinterpret_cast<const float4*>(qwb + (2 * g + 1) * DD);
    const float4 qb1 = *reinterpret_cast<const float4*>(qwb + (2 * g + 1) * DD + 64);

    float4 A0 = make_float4(0.f, 0.f, 0.f, 0.f), A1 = A0;  // acc head 2g
    float4 B0 = A0, B1 = A0;                                // acc head 2g+1
    float den0 = 0.f, den1 = 0.f;

    // 3 rotating single-row buffers (named locals)
    float4 p0a, p0b;
    float4 p1a, p1b;
    float4 p2a, p2b;
    CLD2(p0, 0)
    CLD2(p1, 1)
    CLD2(p2, 2)

    #pragma unroll 1
    for (int k = 0; k < niter3; k += 3) {
        BODY2(p0, k)     CLD2(p0, k + 3)
        BODY2(p1, k + 1) CLD2(p1, k + 4)
        BODY2(p2, k + 2) CLD2(p2, k + 5)
    }

    // ---- write this wave's partial slot ----
    const int oslot = s * 4 + w;
    float* pa_ = part_acc + (((size_t)b * NSLOT + oslot) * NHEADS) * DD + j * 4;
    *reinterpret_cast<float4*>(pa_ + (2 * g) * DD)          = A0;
    *reinterpret_cast<float4*>(pa_ + (2 * g) * DD + 64)     = A1;
    *reinterpret_cast<float4*>(pa_ + (2 * g + 1) * DD)      = B0;
    *reinterpret_cast<float4*>(pa_ + (2 * g + 1) * DD + 64) = B1;
    if (j == 0) {
        float* pd = part_den + ((size_t)b * NSLOT + oslot) * NHEADS;
        pd[2 * g]     = den0;
        pd[2 * g + 1] = den1;
    }
}

// ---------------- kernel 2: combine slots + Wv/Wfc projections --------------
__global__ __launch_bounds__(128) void attn_combine_kernel(
    const float* __restrict__ part_acc,  // [B][NSLOT][8][128]
    const float* __restrict__ part_den,  // [B][NSLOT][8]
    const float* __restrict__ Wv,        // [128][128]
    const float* __restrict__ Wfc,       // [128][128]
    float* __restrict__ out)             // [B][128]
{
    const int b = blockIdx.x;
    const int t = threadIdx.x;   // 128 threads

    __shared__ float s_dn[NHEADS];
    __shared__ float s_ca[NHEADS][132];
    __shared__ float s_o2[HH];

    if (t < NHEADS) {
        float dn = 0.f;
        #pragma unroll
        for (int sp = 0; sp < NSLOT; ++sp)
            dn += part_den[((size_t)b * NSLOT + sp) * NHEADS + t];
        s_dn[t] = dn;
    }
    __syncthreads();

    {
        const int d = t;
        #pragma unroll
        for (int h = 0; h < NHEADS; ++h) {
            float a = 0.f;
            #pragma unroll
            for (int sp = 0; sp < NSLOT; ++sp)
                a += part_acc[(((size_t)b * NSLOT + sp) * NHEADS + h) * DD + d];
            s_ca[h][d] = a / s_dn[h];
        }
    }
    __syncthreads();

    {
        const int h = t >> 4;
        const float* wvr = Wv + (size_t)t * DD;
        float a = 0.f;
        #pragma unroll 4
        for (int d = 0; d < DD; ++d) a = fmaf(s_ca[h][d], wvr[d], a);
        s_o2[t] = a;
    }
    __syncthreads();

    {
        const float* wfc = Wfc + (size_t)t * DD;
        float a = 0.f;
        #pragma unroll 4
        for (int k = 0; k < DD; ++k) a = fmaf(s_o2[k], wfc[k], a);
        out[(size_t)b * HH + t] = a;
    }
}

extern "C" void kernel_launch(void* const* d_in, const int* in_sizes, int n_in,
                              void* d_out, int out_size, void* d_ws, size_t ws_size,
                              hipStream_t stream) {
    const float* state_t = (const float*)d_in[0];
    const float* context = (const float*)d_in[1];
    const int*   mask    = (const int*)d_in[2];
    const float* Wq      = (const float*)d_in[3];
    const float* Wk      = (const float*)d_in[4];
    const float* Wv      = (const float*)d_in[5];
    const float* Wfc     = (const float*)d_in[6];
    float* out = (float*)d_out;

    float* qw       = (float*)d_ws;                                  // 2 MB
    float* part_acc = qw + (size_t)NB * NHEADS * DD;                 // 33.5 MB
    float* part_den = part_acc + (size_t)NB * NSLOT * NHEADS * DD;   // 0.26 MB

    qw_kernel<<<dim3(NB), dim3(256), 0, stream>>>(state_t, Wq, Wk, qw);
    attn_partial_kernel<<<dim3(NSPLIT, NB), dim3(256), 0, stream>>>(
        context, mask, qw, part_acc, part_den);
    attn_combine_kernel<<<dim3(NB), dim3(128), 0, stream>>>(
        part_acc, part_den, Wv, Wfc, out);
}